// Round 1
// baseline (292.369 us; speedup 1.0000x reference)
//
#include <hip/hip_runtime.h>
#include <hip/hip_bf16.h>
#include <math.h>

// Problem: symmetric Hausdorff over B=8 batches, N=M=4096 points, D=2, fp32.
// out = mean_b( max( max_i min_j d(p_i,t_j), max_j min_i d(p_i,t_j) ) )
// Strategy: squared distances everywhere (sqrt once at the end, monotone).
// One block per (i-tile, batch, direction); full opposing set staged in LDS.

#define B 8
#define N 4096
#define TPB 256
#define TILES (N / TPB)   // 16

__global__ __launch_bounds__(64) void hk_init(int* ws) {
    int t = threadIdx.x;
    if (t < 16) ws[t] = 0;   // d^2 >= 0 so 0 is a safe identity for int-bits atomicMax
}

__global__ __launch_bounds__(TPB) void hk_min_max(const float* __restrict__ pred,
                                                  const float* __restrict__ target,
                                                  int* __restrict__ ws) {
    const int tile = blockIdx.x;   // 0..15
    const int b    = blockIdx.y;   // 0..7
    const int dir  = blockIdx.z;   // 0: pred->target, 1: target->pred

    const float* src = (dir == 0) ? pred : target;
    const float* dst = (dir == 0) ? target : pred;

    // Stage the full opposing point set for this batch into LDS (32 KB).
    __shared__ float4 sT[N / 2];          // 4096 float2 viewed as 2048 float4
    const float4* g = reinterpret_cast<const float4*>(dst + (size_t)b * N * 2);
    #pragma unroll
    for (int k = threadIdx.x; k < N / 2; k += TPB) sT[k] = g[k];
    __syncthreads();

    // This thread's source point.
    const int i = tile * TPB + threadIdx.x;
    const float2 p = reinterpret_cast<const float2*>(src + (size_t)b * N * 2)[i];

    const float2* t = reinterpret_cast<const float2*>(sT);
    float mind = 3.402823466e38f;
    #pragma unroll 8
    for (int j = 0; j < N; ++j) {
        float2 q = t[j];                  // broadcast LDS read, conflict-free
        float dx = p.x - q.x;
        float dy = p.y - q.y;
        float d2 = fmaf(dy, dy, dx * dx);
        mind = fminf(mind, d2);
    }

    // Block-level max reduction of per-thread mins.
    float m = mind;
    #pragma unroll
    for (int off = 32; off > 0; off >>= 1)
        m = fmaxf(m, __shfl_down(m, off, 64));

    __shared__ float sred[TPB / 64];
    const int wave = threadIdx.x >> 6;
    const int lane = threadIdx.x & 63;
    if (lane == 0) sred[wave] = m;
    __syncthreads();
    if (threadIdx.x == 0) {
        float bm = sred[0];
        #pragma unroll
        for (int w = 1; w < TPB / 64; ++w) bm = fmaxf(bm, sred[w]);
        // positive floats order identically as ints
        atomicMax(&ws[dir * B + b], __float_as_int(bm));
    }
}

__global__ __launch_bounds__(64) void hk_finalize(const int* __restrict__ ws,
                                                  float* __restrict__ out) {
    if (threadIdx.x == 0) {
        float s = 0.f;
        #pragma unroll
        for (int b = 0; b < B; ++b) {
            float hab2 = __int_as_float(ws[b]);
            float hba2 = __int_as_float(ws[B + b]);
            s += sqrtf(fmaxf(hab2, hba2));
        }
        out[0] = s * (1.0f / B);
    }
}

extern "C" void kernel_launch(void* const* d_in, const int* in_sizes, int n_in,
                              void* d_out, int out_size, void* d_ws, size_t ws_size,
                              hipStream_t stream) {
    const float* pred   = (const float*)d_in[0];
    const float* target = (const float*)d_in[1];
    float* out = (float*)d_out;
    int* ws = (int*)d_ws;

    hk_init<<<1, 64, 0, stream>>>(ws);
    dim3 grid(TILES, B, 2);
    hk_min_max<<<grid, TPB, 0, stream>>>(pred, target, ws);
    hk_finalize<<<1, 64, 0, stream>>>(ws, out);
}

// Round 2
// 86.683 us; speedup vs baseline: 3.3729x; 3.3729x over previous
//
#include <hip/hip_runtime.h>
#include <hip/hip_bf16.h>
#include <math.h>

// Symmetric Hausdorff, B=8, N=M=4096, D=2, fp32.
// Round 2: latency-bound fix. Split j into JC chunks (16x more blocks),
// register-block IB=4 i-points/thread (4 independent min chains, LDS read
// amortized 4x), and use min_j(|q|^2 - 2 p.q) + |p|^2 == min_j d^2
// (monotone shift) for a 3-VALU-op inner pair: fma, fma, fmin.
// Kernel 1 writes per-(i, j-chunk) partial mins to ws; kernel 2 reduces
// (min over chunks, max over i, max over dirs, sqrt, mean).

#define B 8
#define N 4096
#define TPB 256
#define IB 4             // i-points per thread
#define JC 16            // j-chunks per (b,dir)
#define JTILE (N / JC)   // 256 points staged per block

__global__ __launch_bounds__(TPB) void hk_partial(const float* __restrict__ pred,
                                                  const float* __restrict__ target,
                                                  float* __restrict__ pw,
                                                  float* __restrict__ out) {
    const int bx  = blockIdx.x;        // 0..63: [ib: 0..3] x [jc: 0..15]
    const int ib  = bx & 3;
    const int jc  = bx >> 2;
    const int b   = blockIdx.y;
    const int dir = blockIdx.z;

    // Zero the output accumulator once per launch (stream-ordered before hk_reduce).
    if (bx == 0 && b == 0 && dir == 0 && threadIdx.x == 0) out[0] = 0.f;

    const float2* P = reinterpret_cast<const float2*>(dir == 0 ? pred : target) + (size_t)b * N;
    const float2* Q = reinterpret_cast<const float2*>(dir == 0 ? target : pred) + (size_t)b * N;

    // Stage + transform this block's j-chunk: (qx, qy, |q|^2, pad). 4 KB LDS.
    __shared__ float4 sQ[JTILE];
    {
        const int t = threadIdx.x;     // TPB == JTILE
        float2 q = Q[jc * JTILE + t];
        sQ[t] = make_float4(q.x, q.y, fmaf(q.x, q.x, q.y * q.y), 0.f);
    }
    __syncthreads();

    // This thread's IB source points (strided by TPB so stores coalesce).
    float m2x[IB], m2y[IB], pp[IB], mn[IB];
    const int i0 = ib * (TPB * IB) + threadIdx.x;
    #pragma unroll
    for (int k = 0; k < IB; ++k) {
        float2 p = P[i0 + k * TPB];
        m2x[k] = -2.f * p.x;
        m2y[k] = -2.f * p.y;
        pp[k]  = fmaf(p.x, p.x, p.y * p.y);
        mn[k]  = 3.402823466e38f;
    }

    // 3 VALU ops per pair; sQ[j] is a wave-uniform LDS broadcast.
    #pragma unroll 4
    for (int j = 0; j < JTILE; ++j) {
        float4 q = sQ[j];
        #pragma unroll
        for (int k = 0; k < IB; ++k) {
            float t1 = fmaf(m2y[k], q.y, q.z);
            t1 = fmaf(m2x[k], q.x, t1);
            mn[k] = fminf(mn[k], t1);
        }
    }

    // Partial min for this j-chunk, with |p|^2 restored. Layout: [dir][b][jc][i].
    float* dst = pw + (size_t)(((dir * B + b) * JC + jc)) * N;
    #pragma unroll
    for (int k = 0; k < IB; ++k)
        dst[i0 + k * TPB] = mn[k] + pp[k];
}

__global__ __launch_bounds__(TPB) void hk_reduce(const float* __restrict__ pw,
                                                 float* __restrict__ out) {
    const int b = blockIdx.x;
    const int t = threadIdx.x;

    __shared__ float sred[TPB / 64];
    float h2[2];

    for (int dir = 0; dir < 2; ++dir) {
        float mx = -3.402823466e38f;
        for (int i = t; i < N; i += TPB) {
            const float* base = pw + (size_t)((dir * B + b) * JC) * N + i;
            float mnv = base[0];
            #pragma unroll
            for (int jc = 1; jc < JC; ++jc) mnv = fminf(mnv, base[(size_t)jc * N]);
            mx = fmaxf(mx, mnv);
        }
        #pragma unroll
        for (int off = 32; off > 0; off >>= 1)
            mx = fmaxf(mx, __shfl_down(mx, off, 64));
        if ((t & 63) == 0) sred[t >> 6] = mx;
        __syncthreads();
        if (t == 0) {
            float bm = sred[0];
            #pragma unroll
            for (int w = 1; w < TPB / 64; ++w) bm = fmaxf(bm, sred[w]);
            h2[dir] = bm;
        }
        __syncthreads();
    }

    if (t == 0) {
        float s = sqrtf(fmaxf(fmaxf(h2[0], h2[1]), 0.f));
        atomicAdd(out, s * 0.125f);   // mean over B=8
    }
}

extern "C" void kernel_launch(void* const* d_in, const int* in_sizes, int n_in,
                              void* d_out, int out_size, void* d_ws, size_t ws_size,
                              hipStream_t stream) {
    const float* pred   = (const float*)d_in[0];
    const float* target = (const float*)d_in[1];
    float* out = (float*)d_out;
    float* pw  = (float*)d_ws;   // 2*8*16*4096 floats = 4 MB

    dim3 grid(64, B, 2);         // 1024 blocks -> 4 blocks/CU, 16 waves/CU
    hk_partial<<<grid, TPB, 0, stream>>>(pred, target, pw, out);
    hk_reduce<<<B, TPB, 0, stream>>>(pw, out);
}

// Round 3
// 77.456 us; speedup vs baseline: 3.7746x; 1.1191x over previous
//
#include <hip/hip_runtime.h>
#include <hip/hip_bf16.h>
#include <math.h>

// Symmetric Hausdorff, B=8, N=M=4096, D=2, fp32.
// Round 3: (a) j-pairing in the inner loop so the compiler emits v_min3_f32
// (2.5 VALU ops/pair instead of 3), (b) reduce stage widened to 256 blocks
// with per-block output slots (no atomics, no init kernel), (c) 1-block
// finalize writes out[0] directly (no atomicAdd / zeroing).
// Pipeline: hk_partial (1024 blocks) -> hk_maxred (256) -> hk_final (1).
// NOTE: the ~40us fillBuffer seen in rocprof is the harness poisoning the
// 256 MiB workspace; it is inside the measured window and not ours to fix.

#define B 8
#define N 4096
#define TPB 256
#define IB 4             // i-points per thread
#define JC 16            // j-chunks per (b,dir)
#define JTILE (N / JC)   // 256 points staged per block
#define ITILES (N / TPB) // 16 i-tiles for the reduce stage

__global__ __launch_bounds__(TPB) void hk_partial(const float* __restrict__ pred,
                                                  const float* __restrict__ target,
                                                  float* __restrict__ pw) {
    const int bx  = blockIdx.x;        // 0..63: [ib: 0..3] x [jc: 0..15]
    const int ib  = bx & 3;
    const int jc  = bx >> 2;
    const int b   = blockIdx.y;
    const int dir = blockIdx.z;

    const float2* P = reinterpret_cast<const float2*>(dir == 0 ? pred : target) + (size_t)b * N;
    const float2* Q = reinterpret_cast<const float2*>(dir == 0 ? target : pred) + (size_t)b * N;

    // Stage + transform this block's j-chunk: (qx, qy, |q|^2, pad). 4 KB LDS.
    __shared__ float4 sQ[JTILE];
    {
        const int t = threadIdx.x;     // TPB == JTILE
        float2 q = Q[jc * JTILE + t];
        sQ[t] = make_float4(q.x, q.y, fmaf(q.x, q.x, q.y * q.y), 0.f);
    }
    __syncthreads();

    // This thread's IB source points (strided by TPB so stores coalesce).
    float m2x[IB], m2y[IB], pp[IB], mn[IB];
    const int i0 = ib * (TPB * IB) + threadIdx.x;
    #pragma unroll
    for (int k = 0; k < IB; ++k) {
        float2 p = P[i0 + k * TPB];
        m2x[k] = -2.f * p.x;
        m2y[k] = -2.f * p.y;
        pp[k]  = fmaf(p.x, p.x, p.y * p.y);
        mn[k]  = 3.402823466e38f;
    }

    // min_j(|q|^2 - 2 p.q); j processed in pairs so fmin(fmin) -> v_min3_f32.
    // Per 2 pairs: 4 v_fma + 1 v_min3 = 2.5 VALU ops/pair.
    #pragma unroll 2
    for (int j = 0; j < JTILE; j += 2) {
        float4 qa = sQ[j];
        float4 qb = sQ[j + 1];
        #pragma unroll
        for (int k = 0; k < IB; ++k) {
            float ta = fmaf(m2x[k], qa.x, fmaf(m2y[k], qa.y, qa.z));
            float tb = fmaf(m2x[k], qb.x, fmaf(m2y[k], qb.y, qb.z));
            mn[k] = fminf(mn[k], fminf(ta, tb));
        }
    }

    // Partial min for this j-chunk, with |p|^2 restored. Layout: [dir][b][jc][i].
    float* dst = pw + (size_t)((dir * B + b) * JC + jc) * N;
    #pragma unroll
    for (int k = 0; k < IB; ++k)
        dst[i0 + k * TPB] = mn[k] + pp[k];
}

// One block per (i-tile, b, dir): min over 16 jc (coalesced), block max-reduce,
// write to a private slot — no atomics, no init required.
__global__ __launch_bounds__(TPB) void hk_maxred(const float* __restrict__ pw,
                                                 float* __restrict__ pw2) {
    const int tile = blockIdx.x;
    const int b    = blockIdx.y;
    const int dir  = blockIdx.z;
    const int t    = threadIdx.x;

    const float* base = pw + (size_t)((dir * B + b) * JC) * N + tile * TPB + t;
    float mnv = base[0];
    #pragma unroll
    for (int jc = 1; jc < JC; ++jc) mnv = fminf(mnv, base[(size_t)jc * N]);

    float mx = mnv;
    #pragma unroll
    for (int off = 32; off > 0; off >>= 1)
        mx = fmaxf(mx, __shfl_down(mx, off, 64));

    __shared__ float sred[TPB / 64];
    if ((t & 63) == 0) sred[t >> 6] = mx;
    __syncthreads();
    if (t == 0) {
        float bm = sred[0];
        #pragma unroll
        for (int w = 1; w < TPB / 64; ++w) bm = fmaxf(bm, sred[w]);
        pw2[(dir * B + b) * ITILES + tile] = bm;   // [dir][b][tile]
    }
}

// Single block: 256 slots -> 16 (dir,b) maxes -> mean over b of sqrt(max(dirs)).
__global__ __launch_bounds__(64) void hk_final(const float* __restrict__ pw2,
                                               float* __restrict__ out) {
    const int t = threadIdx.x;
    __shared__ float h2[2 * B];
    if (t < 2 * B) {
        float mx = pw2[t * ITILES];
        #pragma unroll
        for (int k = 1; k < ITILES; ++k) mx = fmaxf(mx, pw2[t * ITILES + k]);
        h2[t] = mx;
    }
    __syncthreads();
    if (t == 0) {
        float s = 0.f;
        #pragma unroll
        for (int b = 0; b < B; ++b)
            s += sqrtf(fmaxf(fmaxf(h2[b], h2[B + b]), 0.f));
        out[0] = s * (1.0f / B);
    }
}

extern "C" void kernel_launch(void* const* d_in, const int* in_sizes, int n_in,
                              void* d_out, int out_size, void* d_ws, size_t ws_size,
                              hipStream_t stream) {
    const float* pred   = (const float*)d_in[0];
    const float* target = (const float*)d_in[1];
    float* out = (float*)d_out;
    float* pw  = (float*)d_ws;                       // 2*8*16*4096 floats = 4 MB
    float* pw2 = (float*)((char*)d_ws + (size_t)2 * B * JC * N * sizeof(float)); // 256 floats

    dim3 g1(64, B, 2);           // 1024 blocks -> 4 waves/SIMD
    hk_partial<<<g1, TPB, 0, stream>>>(pred, target, pw);
    dim3 g2(ITILES, B, 2);       // 256 blocks
    hk_maxred<<<g2, TPB, 0, stream>>>(pw, pw2);
    hk_final<<<1, 64, 0, stream>>>(pw2, out);
}